// Round 1
// baseline (12804.703 us; speedup 1.0000x reference)
//
#include <hip/hip_runtime.h>
#include <hip/hip_bf16.h>
#include <stdint.h>
#include <stddef.h>

// Problem constants
#define B_   4096
#define H_   1024
#define L_   256
#define C_   128
#define T_   64
#define H3_  3072

typedef unsigned short u16;
typedef __attribute__((ext_vector_type(8))) short bf16x8;   // 8 bf16 = 4 VGPRs (guide §3, verified on gfx950)
typedef __attribute__((ext_vector_type(4))) float f32x4;

typedef const void __attribute__((address_space(1)))* as1_cvp;
typedef void __attribute__((address_space(3)))* as3_vp;

__device__ __forceinline__ void gl2lds16(const void* g, void* l) {
  // async global->LDS, 16B per lane; LDS dest is wave-uniform base + lane*16
  __builtin_amdgcn_global_load_lds((as1_cvp)g, (as3_vp)l, 16, 0, 0);
}

__device__ __forceinline__ float bf2f(u16 u) {
  union { float f; unsigned int i; } x; x.i = ((unsigned int)u) << 16; return x.f;
}
__device__ __forceinline__ u16 f2bf(float f) {
  union { float f; unsigned int i; } x; x.f = f;
  unsigned int r = x.i + 0x7fffu + ((x.i >> 16) & 1u);  // RNE
  return (u16)(r >> 16);
}
__device__ __forceinline__ float sigm(float x) { return 1.f / (1.f + __expf(-x)); }
__device__ __forceinline__ float tanh_fast(float x) {
  float e = __expf(2.f * x); return 1.f - 2.f / (e + 1.f);
}

// ---------------------------------------------------------------------------
// Generic bf16 GEMM, C[M,N] = A[M,K] @ W[N,K]^T (+bias[n]); m97-style structure.
// 128x128 tile, BK=64, 4 waves each computing 64x64 via 4x4 frags of 16x16x32.
// OUT_MODE: 0 = fp32 C0, 1 = bf16 C0, 2 = bf16 to C0 AND C1 (h1/h2 init).
// M = gridDim.y*128, N = gridDim.x*128 (all dims here are exact multiples).
// ---------------------------------------------------------------------------
template<int OUT_MODE>
__global__ __launch_bounds__(256) void gemm_bt(
    const u16* __restrict__ A, int lda,
    const u16* __restrict__ W, int ldw,
    const float* __restrict__ bias,
    void* __restrict__ C0p, void* __restrict__ C1p, int ldc, int K)
{
  __shared__ __align__(16) u16 As[128 * 64];
  __shared__ __align__(16) u16 Ws[128 * 64];
  const int tid  = threadIdx.x;
  const int wave = tid >> 6, lane = tid & 63;
  const int m0 = blockIdx.y * 128, n0 = blockIdx.x * 128;
  const int wm = (wave >> 1) * 64, wn = (wave & 1) * 64;
  const int lrow = lane & 15, lq = lane >> 4;
  const int arow = wave * 8 + (lane >> 3);   // staging row within a 32-row round
  const int acol = (lane & 7) * 8;           // staging k-offset (8 bf16 = 16B)

  f32x4 acc[4][4] = {};

  const u16* Ag = A + (size_t)m0 * lda;
  const u16* Wg = W + (size_t)n0 * ldw;

  for (int k0 = 0; k0 < K; k0 += 64) {
    __syncthreads();
    #pragma unroll
    for (int rd = 0; rd < 4; rd++) {
      gl2lds16(Ag + (size_t)(rd * 32 + arow) * lda + (k0 + acol), As + rd * 2048 + wave * 512);
      gl2lds16(Wg + (size_t)(rd * 32 + arow) * ldw + (k0 + acol), Ws + rd * 2048 + wave * 512);
    }
    __syncthreads();   // compiler drains vmcnt before s_barrier
    #pragma unroll
    for (int kk = 0; kk < 64; kk += 32) {
      bf16x8 af[4], bw[4];
      #pragma unroll
      for (int i = 0; i < 4; i++)
        af[i] = *(const bf16x8*)&As[(wm + i * 16 + lrow) * 64 + kk + lq * 8];
      #pragma unroll
      for (int j = 0; j < 4; j++)
        bw[j] = *(const bf16x8*)&Ws[(wn + j * 16 + lrow) * 64 + kk + lq * 8];
      #pragma unroll
      for (int i = 0; i < 4; i++)
        #pragma unroll
        for (int j = 0; j < 4; j++)
          acc[i][j] = __builtin_amdgcn_mfma_f32_16x16x32_bf16(af[i], bw[j], acc[i][j], 0, 0, 0);
    }
  }

  // epilogue: C/D layout col = lane&15, row = (lane>>4)*4 + reg  (m89-verified)
  #pragma unroll
  for (int j = 0; j < 4; j++) {
    const int col = n0 + wn + j * 16 + lrow;
    const float bv = bias ? bias[col] : 0.f;
    #pragma unroll
    for (int i = 0; i < 4; i++) {
      #pragma unroll
      for (int r = 0; r < 4; r++) {
        const int row = m0 + wm + i * 16 + lq * 4 + r;
        float v = acc[i][j][r] + bv;
        if (OUT_MODE == 0) {
          ((float*)C0p)[(size_t)row * ldc + col] = v;
        } else if (OUT_MODE == 1) {
          ((u16*)C0p)[(size_t)row * ldc + col] = f2bf(v);
        } else {
          u16 hv = f2bf(v);
          ((u16*)C0p)[(size_t)row * ldc + col] = hv;
          ((u16*)C1p)[(size_t)row * ldc + col] = hv;
        }
      }
    }
  }
}

// ---------------------------------------------------------------------------
// GRU cell, layer 0: gi = E_gi[c[b]] (has b_ih0) + Gz, gh from gemm (has b_hh0).
// In-place h1 update (pure elementwise; gemm that read h1 already finished).
// ---------------------------------------------------------------------------
__global__ __launch_bounds__(256) void gru_cell0(
    const int* __restrict__ c, const float* __restrict__ Egi,
    const u16* __restrict__ Gz, const u16* __restrict__ gh,
    u16* __restrict__ h1)
{
  int i = blockIdx.x * 256 + threadIdx.x;      // 0 .. B*H-1
  int b = i >> 10, j = i & (H_ - 1);
  const float* eg = Egi + (size_t)c[b] * H3_;
  size_t g = (size_t)b * H3_;
  float gir = eg[j]         + bf2f(Gz[g + j]);
  float giz = eg[H_ + j]    + bf2f(Gz[g + H_ + j]);
  float gin = eg[2*H_ + j]  + bf2f(Gz[g + 2*H_ + j]);
  float ghr = bf2f(gh[g + j]);
  float ghz = bf2f(gh[g + H_ + j]);
  float ghn = bf2f(gh[g + 2*H_ + j]);
  float r  = sigm(gir + ghr);
  float zg = sigm(giz + ghz);
  float nn = tanh_fast(gin + r * ghn);
  size_t hi = (size_t)b * H_ + j;
  float h = bf2f(h1[hi]);
  h1[hi] = f2bf((1.f - zg) * nn + zg * h);
}

// GRU cell, layer 1: gi = g1[0] (has b_ih1), gh = g1[1] (has b_hh1). In-place h2.
__global__ __launch_bounds__(256) void gru_cell1(
    const u16* __restrict__ g1, u16* __restrict__ h2)
{
  int i = blockIdx.x * 256 + threadIdx.x;
  int b = i >> 10, j = i & (H_ - 1);
  size_t g = (size_t)b * H3_;
  const u16* gh = g1 + (size_t)B_ * H3_;
  float gir = bf2f(g1[g + j]);
  float giz = bf2f(g1[g + H_ + j]);
  float gin = bf2f(g1[g + 2*H_ + j]);
  float ghr = bf2f(gh[g + j]);
  float ghz = bf2f(gh[g + H_ + j]);
  float ghn = bf2f(gh[g + 2*H_ + j]);
  float r  = sigm(gir + ghr);
  float zg = sigm(giz + ghz);
  float nn = tanh_fast(gin + r * ghn);
  size_t hi = (size_t)b * H_ + j;
  float h = bf2f(h2[hi]);
  h2[hi] = f2bf((1.f - zg) * nn + zg * h);
}

// ---------------------------------------------------------------------------
// out = h2 @ h2o_w[:, :H]^T + Oz (Oz holds z-part + bias); write d_out[:,t,:],
// fused per-row argmax -> c. 64 rows/block, full N=128, K=1024. 64 blocks.
// ---------------------------------------------------------------------------
__global__ __launch_bounds__(256) void out_argmax(
    const u16* __restrict__ h2, const u16* __restrict__ Wo,
    const float* __restrict__ Oz, float* __restrict__ outp,
    int* __restrict__ cnew, int t)
{
  __shared__ __align__(16) u16 As[64 * 64];
  __shared__ __align__(16) u16 Ws[128 * 64];
  const int tid = threadIdx.x, wave = tid >> 6, lane = tid & 63;
  const int b0 = blockIdx.x * 64;
  const int lrow = lane & 15, lq = lane >> 4;
  const int arow = wave * 8 + (lane >> 3);
  const int acol = (lane & 7) * 8;
  f32x4 acc[8] = {};

  for (int k0 = 0; k0 < H_; k0 += 64) {
    __syncthreads();
    #pragma unroll
    for (int rd = 0; rd < 2; rd++)
      gl2lds16(h2 + (size_t)(b0 + rd * 32 + arow) * H_ + k0 + acol, As + rd * 2048 + wave * 512);
    #pragma unroll
    for (int rd = 0; rd < 4; rd++)
      gl2lds16(Wo + (size_t)(rd * 32 + arow) * H_ + k0 + acol, Ws + rd * 2048 + wave * 512);
    __syncthreads();
    #pragma unroll
    for (int kk = 0; kk < 64; kk += 32) {
      bf16x8 af = *(const bf16x8*)&As[(wave * 16 + lrow) * 64 + kk + lq * 8];
      #pragma unroll
      for (int j = 0; j < 8; j++) {
        bf16x8 bw = *(const bf16x8*)&Ws[(j * 16 + lrow) * 64 + kk + lq * 8];
        acc[j] = __builtin_amdgcn_mfma_f32_16x16x32_bf16(af, bw, acc[j], 0, 0, 0);
      }
    }
  }

  #pragma unroll
  for (int r = 0; r < 4; r++) {
    const int row = b0 + wave * 16 + lq * 4 + r;
    float mv = -3.4e38f; int mi = 0;
    #pragma unroll
    for (int j = 0; j < 8; j++) {
      const int col = j * 16 + lrow;
      float v = acc[j][r] + Oz[(size_t)row * C_ + col];
      outp[(size_t)row * (T_ * C_) + t * C_ + col] = v;
      if (v > mv) { mv = v; mi = col; }
    }
    // reduce across the 16 lanes of this quad (xor on bits 0..3 stays in-quad)
    #pragma unroll
    for (int off = 1; off < 16; off <<= 1) {
      float ov = __shfl_xor(mv, off);
      int   oi = __shfl_xor(mi, off);
      if (ov > mv || (ov == mv && oi < mi)) { mv = ov; mi = oi; }
    }
    if (lrow == 0) cnew[row] = mi;
  }
}

// --------------------------- conversion kernels ----------------------------
__global__ __launch_bounds__(256) void conv_bf16_k(const float* __restrict__ s, u16* __restrict__ d, int n) {
  int i = blockIdx.x * 256 + threadIdx.x;
  if (i < n) d[i] = f2bf(s[i]);
}
// src [rows][1280] -> dA [rows][1024] (cols 0..1023), dZ [rows][256] (cols 1024..1279)
__global__ __launch_bounds__(256) void conv_split_k(const float* __restrict__ s, u16* __restrict__ dA,
                                                    u16* __restrict__ dZ, int rows) {
  int i = blockIdx.x * 256 + threadIdx.x;
  if (i >= rows * 1280) return;
  int rr = i / 1280, col = i - rr * 1280;
  float v = s[i];
  if (col < 1024) dA[(size_t)rr * 1024 + col] = f2bf(v);
  else            dZ[(size_t)rr * 256 + (col - 1024)] = f2bf(v);
}
__global__ __launch_bounds__(256) void conv_swish_k(const float* __restrict__ s, u16* __restrict__ d, int n) {
  int i = blockIdx.x * 256 + threadIdx.x;
  if (i < n) { float e = s[i]; d[i] = f2bf(e * sigm(e)); }
}

// ---------------------------------------------------------------------------
static inline char* wsal(char*& p, size_t bytes) {
  char* r = p; p += (bytes + 255) & ~(size_t)255; return r;
}

extern "C" void kernel_launch(void* const* d_in, const int* in_sizes, int n_in,
                              void* d_out, int out_size, void* d_ws, size_t ws_size,
                              hipStream_t stream) {
  const float* z       = (const float*)d_in[0];
  const float* embed_w = (const float*)d_in[1];
  const float* z2h_w   = (const float*)d_in[2];
  const float* z2h_b   = (const float*)d_in[3];
  const float* w_ih0   = (const float*)d_in[4];
  const float* w_hh0   = (const float*)d_in[5];
  const float* b_ih0   = (const float*)d_in[6];
  const float* b_hh0   = (const float*)d_in[7];
  const float* w_ih1   = (const float*)d_in[8];
  const float* w_hh1   = (const float*)d_in[9];
  const float* b_ih1   = (const float*)d_in[10];
  const float* b_hh1   = (const float*)d_in[11];
  const float* h2o_w   = (const float*)d_in[12];
  const float* h2o_b   = (const float*)d_in[13];
  float* outp = (float*)d_out;

  char* p = (char*)d_ws;                                    // ~144 MB total
  u16* whh0  = (u16*)wsal(p, (size_t)H3_ * H_ * 2);
  u16* wih1  = (u16*)wsal(p, (size_t)H3_ * H_ * 2);
  u16* whh1  = (u16*)wsal(p, (size_t)H3_ * H_ * 2);
  u16* wih0a = (u16*)wsal(p, (size_t)H3_ * H_ * 2);
  u16* wih0z = (u16*)wsal(p, (size_t)H3_ * L_ * 2);
  u16* h2oa  = (u16*)wsal(p, (size_t)C_ * H_ * 2);
  u16* h2oz  = (u16*)wsal(p, (size_t)C_ * L_ * 2);
  u16* z2hb  = (u16*)wsal(p, (size_t)H_ * L_ * 2);
  u16* zb    = (u16*)wsal(p, (size_t)B_ * L_ * 2);
  u16* swe   = (u16*)wsal(p, (size_t)C_ * H_ * 2);
  float* Egi = (float*)wsal(p, (size_t)C_ * H3_ * 4);
  u16* Gz    = (u16*)wsal(p, (size_t)B_ * H3_ * 2);
  float* Oz  = (float*)wsal(p, (size_t)B_ * C_ * 4);
  u16* h1    = (u16*)wsal(p, (size_t)B_ * H_ * 2);
  u16* h2    = (u16*)wsal(p, (size_t)B_ * H_ * 2);
  u16* gh0   = (u16*)wsal(p, (size_t)B_ * H3_ * 2);
  u16* g1    = (u16*)wsal(p, (size_t)2 * B_ * H3_ * 2);
  int* cbuf  = (int*)wsal(p, (size_t)B_ * 4);

  // ---- one-time (per call) precompute ----
  conv_bf16_k<<<(B_*L_ + 255)/256, 256, 0, stream>>>(z, zb, B_*L_);
  conv_bf16_k<<<(H_*L_ + 255)/256, 256, 0, stream>>>(z2h_w, z2hb, H_*L_);
  conv_bf16_k<<<(H3_*H_ + 255)/256, 256, 0, stream>>>(w_hh0, whh0, H3_*H_);
  conv_bf16_k<<<(H3_*H_ + 255)/256, 256, 0, stream>>>(w_ih1, wih1, H3_*H_);
  conv_bf16_k<<<(H3_*H_ + 255)/256, 256, 0, stream>>>(w_hh1, whh1, H3_*H_);
  conv_split_k<<<(H3_*1280 + 255)/256, 256, 0, stream>>>(w_ih0, wih0a, wih0z, H3_);
  conv_split_k<<<(C_*1280 + 255)/256, 256, 0, stream>>>(h2o_w, h2oa, h2oz, C_);
  conv_swish_k<<<(C_*H_ + 255)/256, 256, 0, stream>>>(embed_w, swe, C_*H_);
  hipMemsetAsync(cbuf, 0, B_ * sizeof(int), stream);        // c0 = SOS = 0

  // h0 = z @ z2h_w^T + b  -> both h1 and h2
  gemm_bt<2><<<dim3(H_/128, B_/128), 256, 0, stream>>>(zb, L_, z2hb, L_, z2h_b, h1, h2, H_, L_);
  // E_gi[c] = swish(embed)[c] @ w_ih0[:, :H]^T + b_ih0   (kills one GEMM/step)
  gemm_bt<0><<<dim3(H3_/128, 1), 256, 0, stream>>>(swe, H_, wih0a, H_, b_ih0, Egi, nullptr, H3_, H_);
  // Gz = z @ w_ih0[:, H:]^T  (loop-invariant)
  gemm_bt<1><<<dim3(H3_/128, B_/128), 256, 0, stream>>>(zb, L_, wih0z, L_, nullptr, Gz, nullptr, H3_, L_);
  // Oz = z @ h2o_w[:, H:]^T + h2o_b  (loop-invariant)
  gemm_bt<0><<<dim3(1, B_/128), 256, 0, stream>>>(zb, L_, h2oz, L_, h2o_b, Oz, nullptr, C_, L_);

  // ---- 64 sequential decode steps ----
  for (int t = 0; t < T_; t++) {
    // gh0 = h1 @ w_hh0^T + b_hh0
    gemm_bt<1><<<dim3(H3_/128, B_/128), 256, 0, stream>>>(h1, H_, whh0, H_, b_hh0, gh0, nullptr, H3_, H_);
    gru_cell0<<<B_*H_/256, 256, 0, stream>>>(cbuf, Egi, Gz, gh0, h1);
    // gi1 = h1_new @ w_ih1^T + b_ih1 ; gh1 = h2 @ w_hh1^T + b_hh1
    gemm_bt<1><<<dim3(H3_/128, B_/128), 256, 0, stream>>>(h1, H_, wih1, H_, b_ih1, g1, nullptr, H3_, H_);
    gemm_bt<1><<<dim3(H3_/128, B_/128), 256, 0, stream>>>(h2, H_, whh1, H_, b_hh1, g1 + (size_t)B_*H3_, nullptr, H3_, H_);
    gru_cell1<<<B_*H_/256, 256, 0, stream>>>(g1, h2);
    // logits + sample
    out_argmax<<<B_/64, 256, 0, stream>>>(h2, h2oa, Oz, outp, cbuf, t);
  }
}

// Round 2
// 11041.850 us; speedup vs baseline: 1.1597x; 1.1597x over previous
//
#include <hip/hip_runtime.h>
#include <hip/hip_bf16.h>
#include <stdint.h>
#include <stddef.h>

// Problem constants
#define B_   4096
#define H_   1024
#define L_   256
#define C_   128
#define T_   64
#define H3_  3072

typedef unsigned short u16;
typedef __attribute__((ext_vector_type(8))) short bf16x8;   // 8 bf16 = 4 VGPRs
typedef __attribute__((ext_vector_type(4))) float f32x4;

typedef const void __attribute__((address_space(1)))* as1_cvp;
typedef void __attribute__((address_space(3)))* as3_vp;

__device__ __forceinline__ void gl2lds16(const void* g, void* l) {
  __builtin_amdgcn_global_load_lds((as1_cvp)g, (as3_vp)l, 16, 0, 0);
}

__device__ __forceinline__ float bf2f(u16 u) {
  union { float f; unsigned int i; } x; x.i = ((unsigned int)u) << 16; return x.f;
}
__device__ __forceinline__ u16 f2bf(float f) {
  union { float f; unsigned int i; } x; x.f = f;
  unsigned int r = x.i + 0x7fffu + ((x.i >> 16) & 1u);  // RNE
  return (u16)(r >> 16);
}
__device__ __forceinline__ float sigm(float x) { return 1.f / (1.f + __expf(-x)); }
__device__ __forceinline__ float tanh_fast(float x) {
  float e = __expf(2.f * x); return 1.f - 2.f / (e + 1.f);
}

// ---------------------------------------------------------------------------
// 128x128-tile bf16 GEMM body (m97 structure): C[M,N] = A[M,K] @ W[N,K]^T +bias
// OUT_MODE: 0 = fp32 C0, 1 = bf16 C0, 2 = bf16 to C0 AND C1.
// ---------------------------------------------------------------------------
template<int OUT_MODE>
__device__ __forceinline__ void gemm_tile_body(
    u16* As, u16* Ws,
    const u16* __restrict__ A, int lda,
    const u16* __restrict__ W, int ldw,
    const float* __restrict__ bias,
    void* __restrict__ C0p, void* __restrict__ C1p, int ldc, int K,
    int m0, int n0)
{
  const int tid  = threadIdx.x;
  const int wave = tid >> 6, lane = tid & 63;
  const int wm = (wave >> 1) * 64, wn = (wave & 1) * 64;
  const int lrow = lane & 15, lq = lane >> 4;
  const int arow = wave * 8 + (lane >> 3);   // staging row within a 32-row round
  const int acol = (lane & 7) * 8;           // staging k-offset (8 bf16 = 16B)

  f32x4 acc[4][4] = {};

  const u16* Ag = A + (size_t)m0 * lda;
  const u16* Wg = W + (size_t)n0 * ldw;

  for (int k0 = 0; k0 < K; k0 += 64) {
    __syncthreads();
    #pragma unroll
    for (int rd = 0; rd < 4; rd++) {
      gl2lds16(Ag + (size_t)(rd * 32 + arow) * lda + (k0 + acol), As + rd * 2048 + wave * 512);
      gl2lds16(Wg + (size_t)(rd * 32 + arow) * ldw + (k0 + acol), Ws + rd * 2048 + wave * 512);
    }
    __syncthreads();
    #pragma unroll
    for (int kk = 0; kk < 64; kk += 32) {
      bf16x8 af[4], bw[4];
      #pragma unroll
      for (int i = 0; i < 4; i++)
        af[i] = *(const bf16x8*)&As[(wm + i * 16 + lrow) * 64 + kk + lq * 8];
      #pragma unroll
      for (int j = 0; j < 4; j++)
        bw[j] = *(const bf16x8*)&Ws[(wn + j * 16 + lrow) * 64 + kk + lq * 8];
      #pragma unroll
      for (int i = 0; i < 4; i++)
        #pragma unroll
        for (int j = 0; j < 4; j++)
          acc[i][j] = __builtin_amdgcn_mfma_f32_16x16x32_bf16(af[i], bw[j], acc[i][j], 0, 0, 0);
    }
  }

  // epilogue: C/D layout col = lane&15, row = (lane>>4)*4 + reg  (m89-verified)
  #pragma unroll
  for (int j = 0; j < 4; j++) {
    const int col = n0 + wn + j * 16 + lrow;
    const float bv = bias ? bias[col] : 0.f;
    #pragma unroll
    for (int i = 0; i < 4; i++) {
      #pragma unroll
      for (int r = 0; r < 4; r++) {
        const int row = m0 + wm + i * 16 + lq * 4 + r;
        float v = acc[i][j][r] + bv;
        if (OUT_MODE == 0) {
          ((float*)C0p)[(size_t)row * ldc + col] = v;
        } else if (OUT_MODE == 1) {
          ((u16*)C0p)[(size_t)row * ldc + col] = f2bf(v);
        } else {
          u16 hv = f2bf(v);
          ((u16*)C0p)[(size_t)row * ldc + col] = hv;
          ((u16*)C1p)[(size_t)row * ldc + col] = hv;
        }
      }
    }
  }
}

// generic wrapper for precompute launches (plain blockIdx mapping)
template<int OUT_MODE>
__global__ __launch_bounds__(256) void gemm_bt(
    const u16* __restrict__ A, int lda,
    const u16* __restrict__ W, int ldw,
    const float* __restrict__ bias,
    void* __restrict__ C0p, void* __restrict__ C1p, int ldc, int K)
{
  __shared__ __align__(16) u16 As[128 * 64];
  __shared__ __align__(16) u16 Ws[128 * 64];
  gemm_tile_body<OUT_MODE>(As, Ws, A, lda, W, ldw, bias, C0p, C1p, ldc, K,
                           blockIdx.y * 128, blockIdx.x * 128);
}

// ---------------------------------------------------------------------------
// out = h2 @ Wo^T + Oz (Oz holds z-part + bias); writes d_out[:,t,:] and
// per-row argmax -> cnew. 64 batch rows per block, N=128 full, K=1024.
// ---------------------------------------------------------------------------
__device__ __forceinline__ void out_body(
    u16* As, u16* Ws, int ob,
    const u16* __restrict__ h2, const u16* __restrict__ Wo,
    const float* __restrict__ Oz, float* __restrict__ outp,
    int* __restrict__ cnew, int t)
{
  const int tid = threadIdx.x, wave = tid >> 6, lane = tid & 63;
  const int b0 = ob * 64;
  const int lrow = lane & 15, lq = lane >> 4;
  const int arow = wave * 8 + (lane >> 3);
  const int acol = (lane & 7) * 8;
  f32x4 acc[8] = {};

  for (int k0 = 0; k0 < H_; k0 += 64) {
    __syncthreads();
    #pragma unroll
    for (int rd = 0; rd < 2; rd++)
      gl2lds16(h2 + (size_t)(b0 + rd * 32 + arow) * H_ + k0 + acol, As + rd * 2048 + wave * 512);
    #pragma unroll
    for (int rd = 0; rd < 4; rd++)
      gl2lds16(Wo + (size_t)(rd * 32 + arow) * H_ + k0 + acol, Ws + rd * 2048 + wave * 512);
    __syncthreads();
    #pragma unroll
    for (int kk = 0; kk < 64; kk += 32) {
      bf16x8 af = *(const bf16x8*)&As[(wave * 16 + lrow) * 64 + kk + lq * 8];
      #pragma unroll
      for (int j = 0; j < 8; j++) {
        bf16x8 bw = *(const bf16x8*)&Ws[(j * 16 + lrow) * 64 + kk + lq * 8];
        acc[j] = __builtin_amdgcn_mfma_f32_16x16x32_bf16(af, bw, acc[j], 0, 0, 0);
      }
    }
  }

  #pragma unroll
  for (int r = 0; r < 4; r++) {
    const int row = b0 + wave * 16 + lq * 4 + r;
    float mv = -3.4e38f; int mi = 0;
    #pragma unroll
    for (int j = 0; j < 8; j++) {
      const int col = j * 16 + lrow;
      float v = acc[j][r] + Oz[(size_t)row * C_ + col];
      outp[(size_t)row * (T_ * C_) + t * C_ + col] = v;
      if (v > mv) { mv = v; mi = col; }
    }
    #pragma unroll
    for (int off = 1; off < 16; off <<= 1) {
      float ov = __shfl_xor(mv, off);
      int   oi = __shfl_xor(mi, off);
      if (ov > mv || (ov == mv && oi < mi)) { mv = ov; mi = oi; }
    }
    if (lrow == 0) cnew[row] = mi;
  }
}

// ---------------------------------------------------------------------------
// Fused step-front kernel: blocks 0..63 = out_argmax(t-1) (skipped if t<0);
// blocks 64..1599 = combined gh0 = h1@whh0^T and gh1 = h2@whh1^T.
// All three pieces depend only on end-of-previous-step state -> one launch.
// Supertile swizzle (16m x 6n) keeps a ~5.5MB A+W active set for L2 locality.
// ---------------------------------------------------------------------------
__global__ __launch_bounds__(256) void step_front(
    const u16* __restrict__ h1, const u16* __restrict__ h2,
    const u16* __restrict__ whh0, const float* __restrict__ b_hh0, u16* __restrict__ gh0,
    const u16* __restrict__ whh1, const float* __restrict__ b_hh1, u16* __restrict__ gh1,
    const u16* __restrict__ Wo, const float* __restrict__ Oz,
    float* __restrict__ outp, int* __restrict__ cbuf, int tprev)
{
  __shared__ __align__(16) u16 As[128 * 64];
  __shared__ __align__(16) u16 Ws[128 * 64];
  int bid = blockIdx.x;
  if (bid < 64) {
    if (tprev >= 0) out_body(As, Ws, bid, h2, Wo, Oz, outp, cbuf, tprev);
    return;
  }
  bid -= 64;                       // 0..1535 gemm blocks
  const int st = bid / 96, lid = bid % 96;
  const int stm = st & 3, stn = st >> 2;      // 4 m-groups x 4 n-groups
  const int m = stm * 16 + (lid & 15);        // 0..63 (both halves)
  const int n = stn * 6 + (lid >> 4);         // 0..23
  if (m < 32)
    gemm_tile_body<1>(As, Ws, h1, H_, whh0, H_, b_hh0, gh0, nullptr, H3_, H_, m * 128, n * 128);
  else
    gemm_tile_body<1>(As, Ws, h2, H_, whh1, H_, b_hh1, gh1, nullptr, H3_, H_, (m - 32) * 128, n * 128);
}

// gi1 = h1 @ wih1^T + b_ih1 (768 blocks, 2x4 supertile groups)
__global__ __launch_bounds__(256) void gemm_gi1(
    const u16* __restrict__ h1, const u16* __restrict__ wih1,
    const float* __restrict__ b_ih1, u16* __restrict__ gi1)
{
  __shared__ __align__(16) u16 As[128 * 64];
  __shared__ __align__(16) u16 Ws[128 * 64];
  const int bid = blockIdx.x;
  const int st = bid / 96, lid = bid % 96;
  const int stm = st & 1, stn = st >> 1;      // 2 m-groups x 4 n-groups
  const int m = stm * 16 + (lid & 15);        // 0..31
  const int n = stn * 6 + (lid >> 4);         // 0..23
  gemm_tile_body<1>(As, Ws, h1, H_, wih1, H_, b_ih1, gi1, nullptr, H3_, H_, m * 128, n * 128);
}

// ---------------------------------------------------------------------------
// GRU cells, 4 elems/thread, one block per batch row (c[b] wave-uniform).
// ---------------------------------------------------------------------------
__global__ __launch_bounds__(256) void gru_cell0_v(
    const int* __restrict__ c, const float* __restrict__ Egi,
    const u16* __restrict__ Gz, const u16* __restrict__ gh,
    u16* __restrict__ h1)
{
  const int b = blockIdx.x, j = threadIdx.x * 4;
  const float* eg = Egi + (size_t)c[b] * H3_;
  const size_t g = (size_t)b * H3_ + j;
  float4 er = *(const float4*)&eg[j];
  float4 ez = *(const float4*)&eg[H_ + j];
  float4 en = *(const float4*)&eg[2 * H_ + j];
  ushort4 zr = *(const ushort4*)&Gz[g];
  ushort4 zz = *(const ushort4*)&Gz[g + H_];
  ushort4 zn = *(const ushort4*)&Gz[g + 2 * H_];
  ushort4 hr = *(const ushort4*)&gh[g];
  ushort4 hz = *(const ushort4*)&gh[g + H_];
  ushort4 hn = *(const ushort4*)&gh[g + 2 * H_];
  const size_t hi = (size_t)b * H_ + j;
  ushort4 hold = *(const ushort4*)&h1[hi];
  ushort4 outv;
  #pragma unroll
  for (int k = 0; k < 4; k++) {
    float gir = ((const float*)&er)[k] + bf2f(((const u16*)&zr)[k]);
    float giz = ((const float*)&ez)[k] + bf2f(((const u16*)&zz)[k]);
    float gin = ((const float*)&en)[k] + bf2f(((const u16*)&zn)[k]);
    float r  = sigm(gir + bf2f(((const u16*)&hr)[k]));
    float zg = sigm(giz + bf2f(((const u16*)&hz)[k]));
    float nn = tanh_fast(gin + r * bf2f(((const u16*)&hn)[k]));
    float h = bf2f(((const u16*)&hold)[k]);
    ((u16*)&outv)[k] = f2bf((1.f - zg) * nn + zg * h);
  }
  *(ushort4*)&h1[hi] = outv;
}

__global__ __launch_bounds__(256) void gru_cell1_v(
    const u16* __restrict__ gi, const u16* __restrict__ gh,
    u16* __restrict__ h2)
{
  const int b = blockIdx.x, j = threadIdx.x * 4;
  const size_t g = (size_t)b * H3_ + j;
  ushort4 ir = *(const ushort4*)&gi[g];
  ushort4 iz = *(const ushort4*)&gi[g + H_];
  ushort4 in_ = *(const ushort4*)&gi[g + 2 * H_];
  ushort4 hr = *(const ushort4*)&gh[g];
  ushort4 hz = *(const ushort4*)&gh[g + H_];
  ushort4 hn = *(const ushort4*)&gh[g + 2 * H_];
  const size_t hi = (size_t)b * H_ + j;
  ushort4 hold = *(const ushort4*)&h2[hi];
  ushort4 outv;
  #pragma unroll
  for (int k = 0; k < 4; k++) {
    float r  = sigm(bf2f(((const u16*)&ir)[k]) + bf2f(((const u16*)&hr)[k]));
    float zg = sigm(bf2f(((const u16*)&iz)[k]) + bf2f(((const u16*)&hz)[k]));
    float nn = tanh_fast(bf2f(((const u16*)&in_)[k]) + r * bf2f(((const u16*)&hn)[k]));
    float h = bf2f(((const u16*)&hold)[k]);
    ((u16*)&outv)[k] = f2bf((1.f - zg) * nn + zg * h);
  }
  *(ushort4*)&h2[hi] = outv;
}

// --------------------------- conversion kernels ----------------------------
__global__ __launch_bounds__(256) void conv_bf16_k(const float* __restrict__ s, u16* __restrict__ d, int n) {
  int i = blockIdx.x * 256 + threadIdx.x;
  if (i < n) d[i] = f2bf(s[i]);
}
__global__ __launch_bounds__(256) void conv_split_k(const float* __restrict__ s, u16* __restrict__ dA,
                                                    u16* __restrict__ dZ, int rows) {
  int i = blockIdx.x * 256 + threadIdx.x;
  if (i >= rows * 1280) return;
  int rr = i / 1280, col = i - rr * 1280;
  float v = s[i];
  if (col < 1024) dA[(size_t)rr * 1024 + col] = f2bf(v);
  else            dZ[(size_t)rr * 256 + (col - 1024)] = f2bf(v);
}
__global__ __launch_bounds__(256) void conv_swish_k(const float* __restrict__ s, u16* __restrict__ d, int n) {
  int i = blockIdx.x * 256 + threadIdx.x;
  if (i < n) { float e = s[i]; d[i] = f2bf(e * sigm(e)); }
}

// ---------------------------------------------------------------------------
static inline char* wsal(char*& p, size_t bytes) {
  char* r = p; p += (bytes + 255) & ~(size_t)255; return r;
}

extern "C" void kernel_launch(void* const* d_in, const int* in_sizes, int n_in,
                              void* d_out, int out_size, void* d_ws, size_t ws_size,
                              hipStream_t stream) {
  const float* z       = (const float*)d_in[0];
  const float* embed_w = (const float*)d_in[1];
  const float* z2h_w   = (const float*)d_in[2];
  const float* z2h_b   = (const float*)d_in[3];
  const float* w_ih0   = (const float*)d_in[4];
  const float* w_hh0   = (const float*)d_in[5];
  const float* b_ih0   = (const float*)d_in[6];
  const float* b_hh0   = (const float*)d_in[7];
  const float* w_ih1   = (const float*)d_in[8];
  const float* w_hh1   = (const float*)d_in[9];
  const float* b_ih1   = (const float*)d_in[10];
  const float* b_hh1   = (const float*)d_in[11];
  const float* h2o_w   = (const float*)d_in[12];
  const float* h2o_b   = (const float*)d_in[13];
  float* outp = (float*)d_out;

  char* p = (char*)d_ws;
  u16* whh0  = (u16*)wsal(p, (size_t)H3_ * H_ * 2);
  u16* wih1  = (u16*)wsal(p, (size_t)H3_ * H_ * 2);
  u16* whh1  = (u16*)wsal(p, (size_t)H3_ * H_ * 2);
  u16* wih0a = (u16*)wsal(p, (size_t)H3_ * H_ * 2);
  u16* wih0z = (u16*)wsal(p, (size_t)H3_ * L_ * 2);
  u16* h2oa  = (u16*)wsal(p, (size_t)C_ * H_ * 2);
  u16* h2oz  = (u16*)wsal(p, (size_t)C_ * L_ * 2);
  u16* z2hb  = (u16*)wsal(p, (size_t)H_ * L_ * 2);
  u16* zb    = (u16*)wsal(p, (size_t)B_ * L_ * 2);
  u16* swe   = (u16*)wsal(p, (size_t)C_ * H_ * 2);
  float* Egi = (float*)wsal(p, (size_t)C_ * H3_ * 4);
  u16* Gz    = (u16*)wsal(p, (size_t)B_ * H3_ * 2);
  float* Oz  = (float*)wsal(p, (size_t)B_ * C_ * 4);
  u16* h1    = (u16*)wsal(p, (size_t)B_ * H_ * 2);
  u16* h2    = (u16*)wsal(p, (size_t)B_ * H_ * 2);
  u16* gh0   = (u16*)wsal(p, (size_t)B_ * H3_ * 2);
  u16* gh1   = (u16*)wsal(p, (size_t)B_ * H3_ * 2);
  u16* gi1   = (u16*)wsal(p, (size_t)B_ * H3_ * 2);
  int* cbuf  = (int*)wsal(p, (size_t)B_ * 4);

  // ---- one-time (per call) precompute ----
  conv_bf16_k<<<(B_*L_ + 255)/256, 256, 0, stream>>>(z, zb, B_*L_);
  conv_bf16_k<<<(H_*L_ + 255)/256, 256, 0, stream>>>(z2h_w, z2hb, H_*L_);
  conv_bf16_k<<<(H3_*H_ + 255)/256, 256, 0, stream>>>(w_hh0, whh0, H3_*H_);
  conv_bf16_k<<<(H3_*H_ + 255)/256, 256, 0, stream>>>(w_ih1, wih1, H3_*H_);
  conv_bf16_k<<<(H3_*H_ + 255)/256, 256, 0, stream>>>(w_hh1, whh1, H3_*H_);
  conv_split_k<<<(H3_*1280 + 255)/256, 256, 0, stream>>>(w_ih0, wih0a, wih0z, H3_);
  conv_split_k<<<(C_*1280 + 255)/256, 256, 0, stream>>>(h2o_w, h2oa, h2oz, C_);
  conv_swish_k<<<(C_*H_ + 255)/256, 256, 0, stream>>>(embed_w, swe, C_*H_);
  hipMemsetAsync(cbuf, 0, B_ * sizeof(int), stream);        // c0 = SOS = 0

  // h0 = z @ z2h_w^T + b  -> both h1 and h2
  gemm_bt<2><<<dim3(H_/128, B_/128), 256, 0, stream>>>(zb, L_, z2hb, L_, z2h_b, h1, h2, H_, L_);
  // E_gi[c] = swish(embed)[c] @ w_ih0[:, :H]^T + b_ih0
  gemm_bt<0><<<dim3(H3_/128, 1), 256, 0, stream>>>(swe, H_, wih0a, H_, b_ih0, Egi, nullptr, H3_, H_);
  // Gz = z @ w_ih0[:, H:]^T  (loop-invariant)
  gemm_bt<1><<<dim3(H3_/128, B_/128), 256, 0, stream>>>(zb, L_, wih0z, L_, nullptr, Gz, nullptr, H3_, L_);
  // Oz = z @ h2o_w[:, H:]^T + h2o_b  (loop-invariant)
  gemm_bt<0><<<dim3(1, B_/128), 256, 0, stream>>>(zb, L_, h2oz, L_, h2o_b, Oz, nullptr, C_, L_);

  // ---- 64 sequential decode steps: 4 dispatches each ----
  for (int t = 0; t < T_; t++) {
    step_front<<<1600, 256, 0, stream>>>(h1, h2, whh0, b_hh0, gh0, whh1, b_hh1, gh1,
                                         h2oa, Oz, outp, cbuf, t - 1);
    gru_cell0_v<<<B_, 256, 0, stream>>>(cbuf, Egi, Gz, gh0, h1);
    gemm_gi1<<<768, 256, 0, stream>>>(h1, wih1, b_ih1, gi1);
    gru_cell1_v<<<B_, 256, 0, stream>>>(gi1, gh1, h2);
  }
  // final logits/argmax for t = 63 (grid=64 -> only the out portion runs)
  step_front<<<64, 256, 0, stream>>>(h1, h2, whh0, b_hh0, gh0, whh1, b_hh1, gh1,
                                     h2oa, Oz, outp, cbuf, T_ - 1);
}

// Round 3
// 8406.093 us; speedup vs baseline: 1.5233x; 1.3136x over previous
//
#include <hip/hip_runtime.h>
#include <hip/hip_bf16.h>
#include <stdint.h>
#include <stddef.h>

// Problem constants
#define B_   4096
#define H_   1024
#define L_   256
#define C_   128
#define T_   64
#define H3_  3072

typedef unsigned short u16;
typedef __attribute__((ext_vector_type(8))) short bf16x8;   // 8 bf16 = 4 VGPRs
typedef __attribute__((ext_vector_type(4))) float f32x4;

typedef const void __attribute__((address_space(1)))* as1_cvp;
typedef void __attribute__((address_space(3)))* as3_vp;

__device__ __forceinline__ void gl2lds16(const void* g, void* l) {
  __builtin_amdgcn_global_load_lds((as1_cvp)g, (as3_vp)l, 16, 0, 0);
}

__device__ __forceinline__ float bf2f(u16 u) {
  union { float f; unsigned int i; } x; x.i = ((unsigned int)u) << 16; return x.f;
}
__device__ __forceinline__ u16 f2bf(float f) {
  union { float f; unsigned int i; } x; x.f = f;
  unsigned int r = x.i + 0x7fffu + ((x.i >> 16) & 1u);  // RNE
  return (u16)(r >> 16);
}
__device__ __forceinline__ float sigm(float x) { return 1.f / (1.f + __expf(-x)); }
__device__ __forceinline__ float tanh_fast(float x) {
  float e = __expf(2.f * x); return 1.f - 2.f / (e + 1.f);
}

// ---------------------------------------------------------------------------
// 128x128-tile bf16 GEMM body (m97 structure): C[M,N] = A[M,K] @ W[N,K]^T +bias
// OUT_MODE: 0 = fp32 C0, 1 = bf16 C0, 2 = bf16 to C0 AND C1.
// ---------------------------------------------------------------------------
template<int OUT_MODE>
__device__ __forceinline__ void gemm_tile_body(
    u16* As, u16* Ws,
    const u16* __restrict__ A, int lda,
    const u16* __restrict__ W, int ldw,
    const float* __restrict__ bias,
    void* __restrict__ C0p, void* __restrict__ C1p, int ldc, int K,
    int m0, int n0)
{
  const int tid  = threadIdx.x;
  const int wave = tid >> 6, lane = tid & 63;
  const int wm = (wave >> 1) * 64, wn = (wave & 1) * 64;
  const int lrow = lane & 15, lq = lane >> 4;
  const int arow = wave * 8 + (lane >> 3);
  const int acol = (lane & 7) * 8;

  f32x4 acc[4][4] = {};

  const u16* Ag = A + (size_t)m0 * lda;
  const u16* Wg = W + (size_t)n0 * ldw;

  for (int k0 = 0; k0 < K; k0 += 64) {
    __syncthreads();
    #pragma unroll
    for (int rd = 0; rd < 4; rd++) {
      gl2lds16(Ag + (size_t)(rd * 32 + arow) * lda + (k0 + acol), As + rd * 2048 + wave * 512);
      gl2lds16(Wg + (size_t)(rd * 32 + arow) * ldw + (k0 + acol), Ws + rd * 2048 + wave * 512);
    }
    __syncthreads();
    #pragma unroll
    for (int kk = 0; kk < 64; kk += 32) {
      bf16x8 af[4], bw[4];
      #pragma unroll
      for (int i = 0; i < 4; i++)
        af[i] = *(const bf16x8*)&As[(wm + i * 16 + lrow) * 64 + kk + lq * 8];
      #pragma unroll
      for (int j = 0; j < 4; j++)
        bw[j] = *(const bf16x8*)&Ws[(wn + j * 16 + lrow) * 64 + kk + lq * 8];
      #pragma unroll
      for (int i = 0; i < 4; i++)
        #pragma unroll
        for (int j = 0; j < 4; j++)
          acc[i][j] = __builtin_amdgcn_mfma_f32_16x16x32_bf16(af[i], bw[j], acc[i][j], 0, 0, 0);
    }
  }

  #pragma unroll
  for (int j = 0; j < 4; j++) {
    const int col = n0 + wn + j * 16 + lrow;
    const float bv = bias ? bias[col] : 0.f;
    #pragma unroll
    for (int i = 0; i < 4; i++) {
      #pragma unroll
      for (int r = 0; r < 4; r++) {
        const int row = m0 + wm + i * 16 + lq * 4 + r;
        float v = acc[i][j][r] + bv;
        if (OUT_MODE == 0) {
          ((float*)C0p)[(size_t)row * ldc + col] = v;
        } else if (OUT_MODE == 1) {
          ((u16*)C0p)[(size_t)row * ldc + col] = f2bf(v);
        } else {
          u16 hv = f2bf(v);
          ((u16*)C0p)[(size_t)row * ldc + col] = hv;
          ((u16*)C1p)[(size_t)row * ldc + col] = hv;
        }
      }
    }
  }
}

template<int OUT_MODE>
__global__ __launch_bounds__(256) void gemm_bt(
    const u16* __restrict__ A, int lda,
    const u16* __restrict__ W, int ldw,
    const float* __restrict__ bias,
    void* __restrict__ C0p, void* __restrict__ C1p, int ldc, int K)
{
  __shared__ __align__(16) u16 As[128 * 64];
  __shared__ __align__(16) u16 Ws[128 * 64];
  gemm_tile_body<OUT_MODE>(As, Ws, A, lda, W, ldw, bias, C0p, C1p, ldc, K,
                           blockIdx.y * 128, blockIdx.x * 128);
}

// ---------------------------------------------------------------------------
// out = h2 @ Wo^T + Oz; writes d_out[:,t,:], per-row argmax -> cnew.
// ---------------------------------------------------------------------------
__device__ __forceinline__ void out_body(
    u16* As, u16* Ws, int ob,
    const u16* __restrict__ h2, const u16* __restrict__ Wo,
    const float* __restrict__ Oz, float* __restrict__ outp,
    int* __restrict__ cnew, int t)
{
  const int tid = threadIdx.x, wave = tid >> 6, lane = tid & 63;
  const int b0 = ob * 64;
  const int lrow = lane & 15, lq = lane >> 4;
  const int arow = wave * 8 + (lane >> 3);
  const int acol = (lane & 7) * 8;
  f32x4 acc[8] = {};

  for (int k0 = 0; k0 < H_; k0 += 64) {
    __syncthreads();
    #pragma unroll
    for (int rd = 0; rd < 2; rd++)
      gl2lds16(h2 + (size_t)(b0 + rd * 32 + arow) * H_ + k0 + acol, As + rd * 2048 + wave * 512);
    #pragma unroll
    for (int rd = 0; rd < 4; rd++)
      gl2lds16(Wo + (size_t)(rd * 32 + arow) * H_ + k0 + acol, Ws + rd * 2048 + wave * 512);
    __syncthreads();
    #pragma unroll
    for (int kk = 0; kk < 64; kk += 32) {
      bf16x8 af = *(const bf16x8*)&As[(wave * 16 + lrow) * 64 + kk + lq * 8];
      #pragma unroll
      for (int j = 0; j < 8; j++) {
        bf16x8 bw = *(const bf16x8*)&Ws[(j * 16 + lrow) * 64 + kk + lq * 8];
        acc[j] = __builtin_amdgcn_mfma_f32_16x16x32_bf16(af, bw, acc[j], 0, 0, 0);
      }
    }
  }

  #pragma unroll
  for (int r = 0; r < 4; r++) {
    const int row = b0 + wave * 16 + lq * 4 + r;
    float mv = -3.4e38f; int mi = 0;
    #pragma unroll
    for (int j = 0; j < 8; j++) {
      const int col = j * 16 + lrow;
      float v = acc[j][r] + Oz[(size_t)row * C_ + col];
      outp[(size_t)row * (T_ * C_) + t * C_ + col] = v;
      if (v > mv) { mv = v; mi = col; }
    }
    #pragma unroll
    for (int off = 1; off < 16; off <<= 1) {
      float ov = __shfl_xor(mv, off);
      int   oi = __shfl_xor(mi, off);
      if (ov > mv || (ov == mv && oi < mi)) { mv = ov; mi = oi; }
    }
    if (lrow == 0) cnew[row] = mi;
  }
}

// ---------------------------------------------------------------------------
// Step launch 1: blocks 0..63 = out_argmax(t-1); blocks 64..831 = gh0 GEMM
// (h1 @ whh0^T + b_hh0), XCD-swizzled: xcd = g&7 owns n-tiles xcd*3..xcd*3+2
// so each XCD's 768KB weight slice stays L2-resident across all m.
// ---------------------------------------------------------------------------
__global__ __launch_bounds__(256) void step1(
    const u16* __restrict__ h1, const u16* __restrict__ whh0,
    const float* __restrict__ b_hh0, u16* __restrict__ gh0,
    const u16* __restrict__ h2cur, const u16* __restrict__ Wo,
    const float* __restrict__ Oz, float* __restrict__ outp,
    int* __restrict__ cbuf, int tprev)
{
  __shared__ __align__(16) u16 As[128 * 64];
  __shared__ __align__(16) u16 Ws[128 * 64];
  int bid = blockIdx.x;
  if (bid < 64) {
    if (tprev >= 0) out_body(As, Ws, bid, h2cur, Wo, Oz, outp, cbuf, tprev);
    return;
  }
  const int g = bid - 64;            // 0..767
  const int xcd = g & 7, k = g >> 3; // k: 0..95
  const int n = xcd * 3 + (k % 3);   // 0..23
  const int m = k / 3;               // 0..31
  gemm_tile_body<1>(As, Ws, h1, H_, whh0, H_, b_hh0, gh0, nullptr, H3_, H_,
                    m * 128, n * 128);
}

// ---------------------------------------------------------------------------
// gemm_l3: fused layer-1 GRU. Each block computes a 128(batch) x 64(j) tile of
// all 3 gates for BOTH gi1 = h1@wih1^T (phase 1) and gh1 = h2@whh1^T (phase 2).
// r/z gates share fp32 accumulators across phases (i_r+h_r, i_z+h_z); n gates
// kept separate. Epilogue applies the GRU cell -> h2new (ping-pong buffer).
// Wave layout: 2x2 over (128b x 192n); wave-tile 64b x (3 gates x 32 j).
// acc: 24 + 8 = 32 f32x4 = 128 VGPR.
// ---------------------------------------------------------------------------
template<bool PH2>
__device__ __forceinline__ void l3_phase(
    u16* As, u16* Ws,
    const u16* __restrict__ Ag, const u16* __restrict__ Wg, int j0,
    f32x4 acc[3][2][4], f32x4 accN[2][4])
{
  const int tid = threadIdx.x, wave = tid >> 6, lane = tid & 63;
  const int wmh = wave >> 1, wj = wave & 1;
  const int lrow = lane & 15, lq = lane >> 4;
  const int arow = wave * 8 + (lane >> 3);
  const int acol = (lane & 7) * 8;

  for (int k0 = 0; k0 < H_; k0 += 64) {
    __syncthreads();
    #pragma unroll
    for (int rd = 0; rd < 4; rd++)
      gl2lds16(Ag + (size_t)(rd * 32 + arow) * H_ + (k0 + acol), As + rd * 2048 + wave * 512);
    // W rows: gate = rd>>1, jj = (rd&1)*32 + arow
    #pragma unroll
    for (int rd = 0; rd < 6; rd++)
      gl2lds16(Wg + (size_t)((rd >> 1) * 1024 + j0 + (rd & 1) * 32 + arow) * H_ + (k0 + acol),
               Ws + rd * 2048 + wave * 512);
    __syncthreads();
    #pragma unroll
    for (int kk = 0; kk < 64; kk += 32) {
      bf16x8 af[4];
      #pragma unroll
      for (int i = 0; i < 4; i++)
        af[i] = *(const bf16x8*)&As[(wmh * 64 + i * 16 + lrow) * 64 + kk + lq * 8];
      #pragma unroll
      for (int g = 0; g < 3; g++) {
        #pragma unroll
        for (int u = 0; u < 2; u++) {
          bf16x8 bw = *(const bf16x8*)&Ws[(g * 64 + wj * 32 + u * 16 + lrow) * 64 + kk + lq * 8];
          #pragma unroll
          for (int i = 0; i < 4; i++) {
            if (PH2 && g == 2)
              accN[u][i] = __builtin_amdgcn_mfma_f32_16x16x32_bf16(af[i], bw, accN[u][i], 0, 0, 0);
            else
              acc[g][u][i] = __builtin_amdgcn_mfma_f32_16x16x32_bf16(af[i], bw, acc[g][u][i], 0, 0, 0);
          }
        }
      }
    }
  }
}

__global__ __launch_bounds__(256, 2) void gemm_l3(
    const u16* __restrict__ h1, const u16* __restrict__ h2old,
    const u16* __restrict__ wih1, const u16* __restrict__ whh1,
    const float* __restrict__ b_ih1, const float* __restrict__ b_hh1,
    u16* __restrict__ h2new)
{
  __shared__ __align__(16) u16 As[128 * 64];
  __shared__ __align__(16) u16 Ws[192 * 64];
  // XCD swizzle: xcd owns 2 j-slices (1.5MB W resident); consecutive jobs on an
  // XCD alternate j with same m so the A-tile is L2-hot.
  const int bid = blockIdx.x;
  const int xcd = bid & 7, k = bid >> 3;   // k: 0..63
  const int jt = xcd * 2 + (k & 1);        // 0..15
  const int m  = k >> 1;                   // 0..31
  const int m0 = m * 128, j0 = jt * 64;

  f32x4 acc[3][2][4] = {};
  f32x4 accN[2][4] = {};

  l3_phase<false>(As, Ws, h1    + (size_t)m0 * H_, wih1, j0, acc, accN);
  l3_phase<true >(As, Ws, h2old + (size_t)m0 * H_, whh1, j0, acc, accN);

  const int tid = threadIdx.x, wave = tid >> 6, lane = tid & 63;
  const int wmh = wave >> 1, wj = wave & 1;
  const int lrow = lane & 15, lq = lane >> 4;

  #pragma unroll
  for (int u = 0; u < 2; u++) {
    const int j = j0 + wj * 32 + u * 16 + lrow;
    const float bR  = b_ih1[j] + b_hh1[j];
    const float bZ  = b_ih1[H_ + j] + b_hh1[H_ + j];
    const float bNi = b_ih1[2 * H_ + j];
    const float bNh = b_hh1[2 * H_ + j];
    #pragma unroll
    for (int i = 0; i < 4; i++) {
      #pragma unroll
      for (int rr = 0; rr < 4; rr++) {
        const int row = m0 + wmh * 64 + i * 16 + lq * 4 + rr;
        float r  = sigm(acc[0][u][i][rr] + bR);
        float zg = sigm(acc[1][u][i][rr] + bZ);
        float nn = tanh_fast(acc[2][u][i][rr] + bNi + r * (accN[u][i][rr] + bNh));
        float hold = bf2f(h2old[(size_t)row * H_ + j]);
        h2new[(size_t)row * H_ + j] = f2bf((1.f - zg) * nn + zg * hold);
      }
    }
  }
}

// ---------------------------------------------------------------------------
// GRU cell layer 0 (standalone; needs cbuf from out(t-1) -> separate launch).
// Egi is bf16 now (halves the gather traffic).
// ---------------------------------------------------------------------------
__global__ __launch_bounds__(256) void gru_cell0_v(
    const int* __restrict__ c, const u16* __restrict__ Egi,
    const u16* __restrict__ Gz, const u16* __restrict__ gh,
    u16* __restrict__ h1)
{
  const int b = blockIdx.x, j = threadIdx.x * 4;
  const u16* eg = Egi + (size_t)c[b] * H3_ + j;
  const size_t g = (size_t)b * H3_ + j;
  ushort4 er = *(const ushort4*)&eg[0];
  ushort4 ez = *(const ushort4*)&eg[H_];
  ushort4 en = *(const ushort4*)&eg[2 * H_];
  ushort4 zr = *(const ushort4*)&Gz[g];
  ushort4 zz = *(const ushort4*)&Gz[g + H_];
  ushort4 zn = *(const ushort4*)&Gz[g + 2 * H_];
  ushort4 hr = *(const ushort4*)&gh[g];
  ushort4 hz = *(const ushort4*)&gh[g + H_];
  ushort4 hn = *(const ushort4*)&gh[g + 2 * H_];
  const size_t hi = (size_t)b * H_ + j;
  ushort4 hold = *(const ushort4*)&h1[hi];
  ushort4 outv;
  #pragma unroll
  for (int k = 0; k < 4; k++) {
    float gir = bf2f(((const u16*)&er)[k]) + bf2f(((const u16*)&zr)[k]);
    float giz = bf2f(((const u16*)&ez)[k]) + bf2f(((const u16*)&zz)[k]);
    float gin = bf2f(((const u16*)&en)[k]) + bf2f(((const u16*)&zn)[k]);
    float r  = sigm(gir + bf2f(((const u16*)&hr)[k]));
    float zg = sigm(giz + bf2f(((const u16*)&hz)[k]));
    float nn = tanh_fast(gin + r * bf2f(((const u16*)&hn)[k]));
    float h = bf2f(((const u16*)&hold)[k]);
    ((u16*)&outv)[k] = f2bf((1.f - zg) * nn + zg * h);
  }
  *(ushort4*)&h1[hi] = outv;
}

// --------------------------- conversion kernels ----------------------------
__global__ __launch_bounds__(256) void conv_bf16_k(const float* __restrict__ s, u16* __restrict__ d, int n) {
  int i = blockIdx.x * 256 + threadIdx.x;
  if (i < n) d[i] = f2bf(s[i]);
}
__global__ __launch_bounds__(256) void conv_split_k(const float* __restrict__ s, u16* __restrict__ dA,
                                                    u16* __restrict__ dZ, int rows) {
  int i = blockIdx.x * 256 + threadIdx.x;
  if (i >= rows * 1280) return;
  int rr = i / 1280, col = i - rr * 1280;
  float v = s[i];
  if (col < 1024) dA[(size_t)rr * 1024 + col] = f2bf(v);
  else            dZ[(size_t)rr * 256 + (col - 1024)] = f2bf(v);
}
__global__ __launch_bounds__(256) void conv_swish_k(const float* __restrict__ s, u16* __restrict__ d, int n) {
  int i = blockIdx.x * 256 + threadIdx.x;
  if (i < n) { float e = s[i]; d[i] = f2bf(e * sigm(e)); }
}

// ---------------------------------------------------------------------------
static inline char* wsal(char*& p, size_t bytes) {
  char* r = p; p += (bytes + 255) & ~(size_t)255; return r;
}

extern "C" void kernel_launch(void* const* d_in, const int* in_sizes, int n_in,
                              void* d_out, int out_size, void* d_ws, size_t ws_size,
                              hipStream_t stream) {
  const float* z       = (const float*)d_in[0];
  const float* embed_w = (const float*)d_in[1];
  const float* z2h_w   = (const float*)d_in[2];
  const float* z2h_b   = (const float*)d_in[3];
  const float* w_ih0   = (const float*)d_in[4];
  const float* w_hh0   = (const float*)d_in[5];
  const float* b_ih0   = (const float*)d_in[6];
  const float* b_hh0   = (const float*)d_in[7];
  const float* w_ih1   = (const float*)d_in[8];
  const float* w_hh1   = (const float*)d_in[9];
  const float* b_ih1   = (const float*)d_in[10];
  const float* b_hh1   = (const float*)d_in[11];
  const float* h2o_w   = (const float*)d_in[12];
  const float* h2o_b   = (const float*)d_in[13];
  float* outp = (float*)d_out;

  char* p = (char*)d_ws;
  u16* whh0  = (u16*)wsal(p, (size_t)H3_ * H_ * 2);
  u16* wih1  = (u16*)wsal(p, (size_t)H3_ * H_ * 2);
  u16* whh1  = (u16*)wsal(p, (size_t)H3_ * H_ * 2);
  u16* wih0a = (u16*)wsal(p, (size_t)H3_ * H_ * 2);
  u16* wih0z = (u16*)wsal(p, (size_t)H3_ * L_ * 2);
  u16* h2oa  = (u16*)wsal(p, (size_t)C_ * H_ * 2);
  u16* h2oz  = (u16*)wsal(p, (size_t)C_ * L_ * 2);
  u16* z2hb  = (u16*)wsal(p, (size_t)H_ * L_ * 2);
  u16* zb    = (u16*)wsal(p, (size_t)B_ * L_ * 2);
  u16* swe   = (u16*)wsal(p, (size_t)C_ * H_ * 2);
  u16* EgiB  = (u16*)wsal(p, (size_t)C_ * H3_ * 2);
  u16* Gz    = (u16*)wsal(p, (size_t)B_ * H3_ * 2);
  float* Oz  = (float*)wsal(p, (size_t)B_ * C_ * 4);
  u16* h1    = (u16*)wsal(p, (size_t)B_ * H_ * 2);
  u16* h2a   = (u16*)wsal(p, (size_t)B_ * H_ * 2);
  u16* h2b   = (u16*)wsal(p, (size_t)B_ * H_ * 2);
  u16* gh0   = (u16*)wsal(p, (size_t)B_ * H3_ * 2);
  int* cbuf  = (int*)wsal(p, (size_t)B_ * 4);

  // ---- one-time (per call) precompute ----
  conv_bf16_k<<<(B_*L_ + 255)/256, 256, 0, stream>>>(z, zb, B_*L_);
  conv_bf16_k<<<(H_*L_ + 255)/256, 256, 0, stream>>>(z2h_w, z2hb, H_*L_);
  conv_bf16_k<<<(H3_*H_ + 255)/256, 256, 0, stream>>>(w_hh0, whh0, H3_*H_);
  conv_bf16_k<<<(H3_*H_ + 255)/256, 256, 0, stream>>>(w_ih1, wih1, H3_*H_);
  conv_bf16_k<<<(H3_*H_ + 255)/256, 256, 0, stream>>>(w_hh1, whh1, H3_*H_);
  conv_split_k<<<(H3_*1280 + 255)/256, 256, 0, stream>>>(w_ih0, wih0a, wih0z, H3_);
  conv_split_k<<<(C_*1280 + 255)/256, 256, 0, stream>>>(h2o_w, h2oa, h2oz, C_);
  conv_swish_k<<<(C_*H_ + 255)/256, 256, 0, stream>>>(embed_w, swe, C_*H_);
  hipMemsetAsync(cbuf, 0, B_ * sizeof(int), stream);        // c0 = SOS = 0

  // h0 = z @ z2h_w^T + b  -> h1 and h2a
  gemm_bt<2><<<dim3(H_/128, B_/128), 256, 0, stream>>>(zb, L_, z2hb, L_, z2h_b, h1, h2a, H_, L_);
  // E_gi[c] = swish(embed)[c] @ w_ih0[:, :H]^T + b_ih0   (bf16)
  gemm_bt<1><<<dim3(H3_/128, 1), 256, 0, stream>>>(swe, H_, wih0a, H_, b_ih0, EgiB, nullptr, H3_, H_);
  // Gz = z @ w_ih0[:, H:]^T  (loop-invariant)
  gemm_bt<1><<<dim3(H3_/128, B_/128), 256, 0, stream>>>(zb, L_, wih0z, L_, nullptr, Gz, nullptr, H3_, L_);
  // Oz = z @ h2o_w[:, H:]^T + h2o_b  (loop-invariant)
  gemm_bt<0><<<dim3(1, B_/128), 256, 0, stream>>>(zb, L_, h2oz, L_, h2o_b, Oz, nullptr, C_, L_);

  // ---- 64 sequential decode steps: 3 dispatches each ----
  for (int t = 0; t < T_; t++) {
    const u16* h2cur = (t & 1) ? h2b : h2a;
    u16*       h2nxt = (t & 1) ? h2a : h2b;
    // out(t-1) [64 blocks] + gh0 = h1 @ whh0^T + b_hh0 [768 blocks]
    step1<<<832, 256, 0, stream>>>(h1, whh0, b_hh0, gh0, h2cur, h2oa, Oz, outp, cbuf, t - 1);
    // h1 <- GRUcell0(Egi[c], Gz, gh0, h1)
    gru_cell0_v<<<B_, 256, 0, stream>>>(cbuf, EgiB, Gz, gh0, h1);
    // h2nxt <- GRUcell1(h1@wih1^T, h2cur@whh1^T, h2cur)   (fused dual GEMM)
    gemm_l3<<<512, 256, 0, stream>>>(h1, h2cur, wih1, whh1, b_ih1, b_hh1, h2nxt);
  }
  // final logits/argmax for t = 63 (h2 state lives in h2a after t=63)
  step1<<<64, 256, 0, stream>>>(h1, whh0, b_hh0, gh0, h2a, h2oa, Oz, outp, cbuf, T_ - 1);
}